// Round 9
// baseline (128.024 us; speedup 1.0000x reference)
//
#include <hip/hip_runtime.h>

#define BB 16
#define NN 2048
#define DIN 160
#define IS 32
#define NCAT 64
#define EMBD 64
#define NCTX 2047
#define NT1 64               // 32-col tiles per batch (K1)
#define GRID1 (BB * NT1)     // 1024
#define SS1 34               // LDS row stride (floats) for xs[96][SS1]
#define NPART NT1            // partials per batch
#define USTRIDE (NPART * 1024)  // per-batch float stride in Pg region; U reuses head
#define SS2 34               // k_out staging stride

// ---------------------------------------------------------------------------
// K1: per-tile partial G = xq.xq^T (32x32), K = xcat.xq^T (64x32), 32-col
// tiles. Block 256 = 4 waves; wave mg covers 8 m's; lane (i4,d4) owns a 4x4
// G-tile and 8x4 K-tile. LDS: staging xs[96][34] UNIONED with cbuf (39.9 KB
// total, temporally disjoint, barrier-separated) -> 4 blocks/CU (was 2 at
// 65 KB). Grid 1024 -> 16 waves/CU vs old 8: doubles latency hiding.
// ---------------------------------------------------------------------------
__global__ __launch_bounds__(256, 4) void k_gram(
    const float* __restrict__ x,
    float* __restrict__ Pg, float* __restrict__ Pk)
{
    __shared__ float smem[3 * 64 * 52];  // 39,936 B; xs (3264 fl) ∪ cbuf (9984 fl)
    float* xs = smem;
    float* cbuf = smem;
    const int t = threadIdx.x;
    const int blk = blockIdx.x;
    const int b = blk >> 6;
    const int tile = blk & 63;
    const int n0 = tile << 5;
    const float* xb = x + (size_t)b * DIN * NN;

    // stage rows 0..95 x 32 cols (coalesced float2; mask out global col 2047)
    for (int idx = t; idx < 96 * 16; idx += 256) {
        const int r = idx >> 4;
        const int mc = (idx & 15) << 1;
        float2 v = *(const float2*)&xb[r * NN + n0 + mc];
        if (n0 + mc + 1 == NCTX) v.y = 0.f;
        *(float2*)&xs[r * SS1 + mc] = v;
    }
    __syncthreads();

    const int mg = t >> 6;      // wave id -> m range (8 cols each)
    const int lane = t & 63;
    const int i4 = lane >> 3;   // 0..7
    const int d4 = lane & 7;    // 0..7
    const int i0 = i4 << 2;
    const int d0 = d4 << 2;
    const int m0 = mg << 3;

    float g[4][4], kk[8][4];
#pragma unroll
    for (int ii = 0; ii < 4; ii++)
#pragma unroll
        for (int jj = 0; jj < 4; jj++) g[ii][jj] = 0.f;
#pragma unroll
    for (int ii = 0; ii < 8; ii++)
#pragma unroll
        for (int jj = 0; jj < 4; jj++) kk[ii][jj] = 0.f;

    for (int m = m0; m < m0 + 8; m += 2) {
        float2 q[4], a[4], c[8];
#pragma unroll
        for (int j = 0; j < 4; j++) q[j] = *(const float2*)&xs[(d0 + j) * SS1 + m];
#pragma unroll
        for (int j = 0; j < 4; j++) a[j] = *(const float2*)&xs[(i0 + j) * SS1 + m];
#pragma unroll
        for (int j = 0; j < 8; j++) c[j] = *(const float2*)&xs[(32 + i4 + 8 * j) * SS1 + m];
#pragma unroll
        for (int ii = 0; ii < 4; ii++)
#pragma unroll
            for (int jj = 0; jj < 4; jj++)
                g[ii][jj] += a[ii].x * q[jj].x + a[ii].y * q[jj].y;
#pragma unroll
        for (int ii = 0; ii < 8; ii++)
#pragma unroll
            for (int jj = 0; jj < 4; jj++)
                kk[ii][jj] += c[ii].x * q[jj].x + c[ii].y * q[jj].y;
    }

    __syncthreads();  // all xs reads complete before cbuf overwrites the union

    // cross-wave reduce via cbuf (stride 52 spreads banks)
    if (mg > 0) {
        float* p = cbuf + ((mg - 1) * 64 + lane) * 52;
#pragma unroll
        for (int ii = 0; ii < 4; ii++) *(float4*)&p[ii * 4] = *(float4*)&g[ii][0];
#pragma unroll
        for (int ii = 0; ii < 8; ii++) *(float4*)&p[16 + ii * 4] = *(float4*)&kk[ii][0];
    }
    __syncthreads();
    if (mg == 0) {
#pragma unroll
        for (int w = 0; w < 3; w++) {
            const float* p = cbuf + (w * 64 + lane) * 52;
#pragma unroll
            for (int ii = 0; ii < 4; ii++) {
                float4 v = *(const float4*)&p[ii * 4];
                g[ii][0] += v.x; g[ii][1] += v.y; g[ii][2] += v.z; g[ii][3] += v.w;
            }
#pragma unroll
            for (int ii = 0; ii < 8; ii++) {
                float4 v = *(const float4*)&p[16 + ii * 4];
                kk[ii][0] += v.x; kk[ii][1] += v.y; kk[ii][2] += v.z; kk[ii][3] += v.w;
            }
        }
        float* pg = Pg + (size_t)blk * 1024;
#pragma unroll
        for (int ii = 0; ii < 4; ii++)
            *(float4*)&pg[(i0 + ii) * 32 + d0] = *(float4*)&g[ii][0];
        float* pk = Pk + (size_t)blk * 2048;
#pragma unroll
        for (int ii = 0; ii < 8; ii++)
            *(float4*)&pk[(i4 + 8 * ii) * 32 + d0] = *(float4*)&kk[ii][0];
    }
}

// ---------------------------------------------------------------------------
// K2a: one block per batch. Reduce the 64 partials -> G (32x32), K (64x32);
// run the tiny layer chain; write U (64x32, U[c][d]) into the head of this
// batch's Pg region (barrier-ordered within the only block touching it).
// NOTE: PgU deliberately NOT __restrict__ (read+write alias).
// ---------------------------------------------------------------------------
__global__ __launch_bounds__(256) void k_chain(
    float* PgU, const float* __restrict__ Pk,
    const float* __restrict__ alpha, const float* __restrict__ kp,
    const float* __restrict__ emb, const float* __restrict__ Mm)
{
    __shared__ float G_s[32][36];
    __shared__ float K_s[64][36];
    __shared__ float C_s[64][36];
    __shared__ float W_s[64][36];
    __shared__ float T_s[64][36];
    const int t = threadIdx.x;
    const int b = blockIdx.x;

    // ---- reduce partials ----
    {
        const int row = t >> 3, col = (t & 7) << 2;
        float4 s = {0, 0, 0, 0};
        const float* base = PgU + (size_t)b * USTRIDE + row * 32 + col;
#pragma unroll 8
        for (int p = 0; p < NPART; p++) {
            float4 v = *(const float4*)(base + (size_t)p * 1024);
            s.x += v.x; s.y += v.y; s.z += v.z; s.w += v.w;
        }
        *(float4*)&G_s[row][col] = s;
    }
    {
        const int row0 = t >> 2, col = (t & 3) << 3;
        const float* base = Pk + (size_t)b * NPART * 2048 + row0 * 32 + col;
        float4 s0 = {0, 0, 0, 0}, s1 = {0, 0, 0, 0};
#pragma unroll 8
        for (int p = 0; p < NPART; p++) {
            float4 v0 = *(const float4*)(base + (size_t)p * 2048);
            float4 v1 = *(const float4*)(base + (size_t)p * 2048 + 4);
            s0.x += v0.x; s0.y += v0.y; s0.z += v0.z; s0.w += v0.w;
            s1.x += v1.x; s1.y += v1.y; s1.z += v1.z; s1.w += v1.w;
        }
        *(float4*)&K_s[row0][col] = s0;
        *(float4*)&K_s[row0][col + 4] = s1;
    }
    __syncthreads();

    // ---- tiny chain: C0 = emb.K; l: W += f*C; C += M.(f*C.G) (l<2) ----
    const int r  = t >> 2;         // 0..63
    const int dd = (t & 3) << 3;   // 0,8,16,24
    {
        const float* er = emb + r * EMBD;
        float acc[8];
#pragma unroll
        for (int j = 0; j < 8; j++) acc[j] = 0.f;
        for (int c = 0; c < 64; c++) {
            const float e = er[c];
#pragma unroll
            for (int j = 0; j < 8; j++) acc[j] += e * K_s[c][dd + j];
        }
#pragma unroll
        for (int j = 0; j < 8; j++) C_s[r][dd + j] = acc[j];
    }
    __syncthreads();

    const float scale = kp[0] * (1.f / (float)NCTX);
    for (int l = 0; l < 3; l++) {
        const float f = scale * alpha[l * EMBD + r];
#pragma unroll
        for (int j = 0; j < 8; j++) {
            const float w = f * C_s[r][dd + j];
            if (l == 0) W_s[r][dd + j] = w; else W_s[r][dd + j] += w;
        }
        if (l < 2) {
            float tacc[8];
#pragma unroll
            for (int j = 0; j < 8; j++) tacc[j] = 0.f;
            for (int d = 0; d < 32; d++) {
                const float cv = C_s[r][d];
#pragma unroll
                for (int j = 0; j < 8; j++) tacc[j] += cv * G_s[d][dd + j];
            }
#pragma unroll
            for (int j = 0; j < 8; j++) T_s[r][dd + j] = f * tacc[j];
            __syncthreads();
            const float* Mr = Mm + r * EMBD;
            float uacc[8];
#pragma unroll
            for (int j = 0; j < 8; j++) uacc[j] = 0.f;
            for (int jj = 0; jj < 64; jj++) {
                const float mv = Mr[jj];
#pragma unroll
                for (int j = 0; j < 8; j++) uacc[j] += mv * T_s[jj][dd + j];
            }
#pragma unroll
            for (int j = 0; j < 8; j++) C_s[r][dd + j] += uacc[j];
            __syncthreads();
        }
    }
    __syncthreads();

    // ---- U[c][d] = sum_e emb[e][c] * W[e][d]; write straight to global ----
    {
        float acc[8];
#pragma unroll
        for (int j = 0; j < 8; j++) acc[j] = 0.f;
        for (int e = 0; e < 64; e++) {
            const float ev = emb[e * EMBD + r];
#pragma unroll
            for (int j = 0; j < 8; j++) acc[j] += ev * W_s[e][dd + j];
        }
        float* ub = PgU + (size_t)b * USTRIDE + r * 32 + dd;
        float4 v0 = {acc[0], acc[1], acc[2], acc[3]};
        float4 v1 = {acc[4], acc[5], acc[6], acc[7]};
        *(float4*)&ub[0] = v0;
        *(float4*)&ub[4] = v1;
    }
}

// ---------------------------------------------------------------------------
// K2b: epilogue. Grid 1024 = 16 b x 64 tiles of 32 cols; block 256 = 4 waves;
// thread (h = t>>5 owns 8 cats, nl = t&31 = col). LDS 29.6 KB (was 50) ->
// 4 blocks/CU via grid (16 waves/CU vs old 8). og[48] VGPR array replaced by
// lg_s re-reads (conflict-free: 65 ≡ 1 mod 32) to fit the 128-VGPR budget.
// ---------------------------------------------------------------------------
__global__ __launch_bounds__(256, 4) void k_out(
    const float* __restrict__ x, const float* __restrict__ Ug,
    const float* __restrict__ emb, float* __restrict__ out)
{
    __shared__ float U_s[64][32];      // 8 KB
    __shared__ float xt_s[96 * SS2];   // 13 KB; r<32 = xq rows, r>=32 = tail rows
    __shared__ float lg_s[32 * 65];    // 8.3 KB; [col][cat]
    const int t = threadIdx.x;
    const int blk = blockIdx.x;
    const int b = blk >> 6;
    const int tile = blk & 63;
    const int n0 = tile << 5;
    const float* xb = x + (size_t)b * DIN * NN;

    // stage U (2048 floats) coalesced
    {
        const float* ub = Ug + (size_t)b * USTRIDE + t * 8;
        float4 v0 = *(const float4*)&ub[0];
        float4 v1 = *(const float4*)&ub[4];
        float* d = &U_s[0][0] + t * 8;
        *(float4*)&d[0] = v0;
        *(float4*)&d[4] = v1;
    }
    // stage x rows 0..31 (xq) and 96..159 (tail) -> xt rows 0..95
    for (int idx = t; idx < 96 * 16; idx += 256) {
        const int r = idx >> 4;
        const int mc = (idx & 15) << 1;
        const int gr = (r < IS) ? r : (r + NCAT);
        float2 v = *(const float2*)&xb[gr * NN + n0 + mc];
        *(float2*)&xt_s[r * SS2 + mc] = v;
    }
    __syncthreads();

    const int nl = t & 31;        // col in tile
    const int h = t >> 5;         // cat-eighth
    const int c0 = h << 3;
    const int n = n0 + nl;

    float xq[IS];
#pragma unroll
    for (int d = 0; d < IS; d++) xq[d] = xt_s[d * SS2 + nl];

    float lg[8];
#pragma unroll
    for (int cl = 0; cl < 8; cl++) {
        const float* Ur = &U_s[c0 + cl][0];
        float s = 0.f;
#pragma unroll
        for (int k = 0; k < 8; k++) {
            float4 u = *(const float4*)&Ur[4 * k];
            s += u.x * xq[4*k] + u.y * xq[4*k+1] + u.z * xq[4*k+2] + u.w * xq[4*k+3];
        }
        lg[cl] = s;
    }
#pragma unroll 8
    for (int e = 0; e < 64; e++) {
        const float tv = xt_s[(IS + e) * SS2 + nl];
        const float* er = emb + e * EMBD + c0;  // 32B-aligned
        float4 e0 = *(const float4*)&er[0];
        float4 e1 = *(const float4*)&er[4];
        lg[0] += e0.x * tv; lg[1] += e0.y * tv; lg[2] += e0.z * tv; lg[3] += e0.w * tv;
        lg[4] += e1.x * tv; lg[5] += e1.y * tv; lg[6] += e1.z * tv; lg[7] += e1.w * tv;
    }

    const size_t base = ((size_t)b * NN + n) * (size_t)NCAT;
    float* lo = out + base + c0;
    {
        float4 v0 = {lg[0], lg[1], lg[2], lg[3]};
        float4 v1 = {lg[4], lg[5], lg[6], lg[7]};
        *(float4*)&lo[0] = v0;
        *(float4*)&lo[4] = v1;
    }
    float* ls = &lg_s[nl * 65 + c0];
#pragma unroll
    for (int cl = 0; cl < 8; cl++) ls[cl] = lg[cl];
    __syncthreads();

    // softmax over 64 cats: two LDS passes (bank = (nl+c)%32, conflict-free)
    const float* row = &lg_s[nl * 65];
    float mx = row[0];
#pragma unroll
    for (int c = 1; c < 64; c++) mx = fmaxf(mx, row[c]);

    float p[8];
    float sum = 0.f;
#pragma unroll
    for (int c = 0; c < 64; c++) {
        const float e = __expf(row[c] - mx);
        sum += e;
        if ((c >> 3) == h) p[c & 7] = e;   // static index (c unrolled)
    }

    const float inv = 1.f / sum;
    float* po = out + (size_t)BB * NN * NCAT + base + c0;
    {
        float4 v0 = {p[0]*inv, p[1]*inv, p[2]*inv, p[3]*inv};
        float4 v1 = {p[4]*inv, p[5]*inv, p[6]*inv, p[7]*inv};
        *(float4*)&po[0] = v0;
        *(float4*)&po[4] = v1;
    }
}

extern "C" void kernel_launch(void* const* d_in, const int* in_sizes, int n_in,
                              void* d_out, int out_size, void* d_ws, size_t ws_size,
                              hipStream_t stream) {
    const float* x     = (const float*)d_in[0];
    const float* alpha = (const float*)d_in[1];
    const float* kp    = (const float*)d_in[2];
    const float* emb   = (const float*)d_in[3];
    const float* Mmat  = (const float*)d_in[4];
    float* out = (float*)d_out;

    float* Pg = (float*)d_ws;                 // 1024 * 1024 floats (U reuses head/batch)
    float* Pk = Pg + (size_t)GRID1 * 1024;    // 1024 * 2048 floats

    k_gram <<<GRID1, 256, 0, stream>>>(x, Pg, Pk);
    k_chain<<<BB,    256, 0, stream>>>(Pg, Pk, alpha, kp, emb, Mmat);
    k_out  <<<BB*64, 256, 0, stream>>>(x, Pg, emb, out);
}

// Round 10
// 124.215 us; speedup vs baseline: 1.0307x; 1.0307x over previous
//
#include <hip/hip_runtime.h>

#define BB 16
#define NN 2048
#define DIN 160
#define IS 32
#define NCAT 64
#define EMBD 64
#define NCTX 2047
#define NT1 64               // 32-col tiles per batch (K1)
#define GRID1 (BB * NT1)     // 1024
#define SS1 34               // LDS row stride (floats) for xs[96][SS1]
#define NPART NT1            // partials per batch
#define USTRIDE (NPART * 1024)  // per-batch float stride in Pg region; U reuses head
#define SS2 34               // k_out staging stride
// R (reduced G|K, [b][96][32]) lives after Pg and Pk in ws
#define ROFF ((size_t)GRID1 * 1024 + (size_t)GRID1 * 2048)

// ---------------------------------------------------------------------------
// K1: per-tile partial G = xq.xq^T (32x32), K = xcat.xq^T (64x32), 32-col
// tiles. 4 blocks/CU (union'd LDS 39.9 KB), grid 1024.  [UNCHANGED r9]
// ---------------------------------------------------------------------------
__global__ __launch_bounds__(256, 4) void k_gram(
    const float* __restrict__ x,
    float* __restrict__ Pg, float* __restrict__ Pk)
{
    __shared__ float smem[3 * 64 * 52];  // 39,936 B; xs (3264 fl) ∪ cbuf (9984 fl)
    float* xs = smem;
    float* cbuf = smem;
    const int t = threadIdx.x;
    const int blk = blockIdx.x;
    const int b = blk >> 6;
    const int tile = blk & 63;
    const int n0 = tile << 5;
    const float* xb = x + (size_t)b * DIN * NN;

    for (int idx = t; idx < 96 * 16; idx += 256) {
        const int r = idx >> 4;
        const int mc = (idx & 15) << 1;
        float2 v = *(const float2*)&xb[r * NN + n0 + mc];
        if (n0 + mc + 1 == NCTX) v.y = 0.f;
        *(float2*)&xs[r * SS1 + mc] = v;
    }
    __syncthreads();

    const int mg = t >> 6;
    const int lane = t & 63;
    const int i4 = lane >> 3;
    const int d4 = lane & 7;
    const int i0 = i4 << 2;
    const int d0 = d4 << 2;
    const int m0 = mg << 3;

    float g[4][4], kk[8][4];
#pragma unroll
    for (int ii = 0; ii < 4; ii++)
#pragma unroll
        for (int jj = 0; jj < 4; jj++) g[ii][jj] = 0.f;
#pragma unroll
    for (int ii = 0; ii < 8; ii++)
#pragma unroll
        for (int jj = 0; jj < 4; jj++) kk[ii][jj] = 0.f;

    for (int m = m0; m < m0 + 8; m += 2) {
        float2 q[4], a[4], c[8];
#pragma unroll
        for (int j = 0; j < 4; j++) q[j] = *(const float2*)&xs[(d0 + j) * SS1 + m];
#pragma unroll
        for (int j = 0; j < 4; j++) a[j] = *(const float2*)&xs[(i0 + j) * SS1 + m];
#pragma unroll
        for (int j = 0; j < 8; j++) c[j] = *(const float2*)&xs[(32 + i4 + 8 * j) * SS1 + m];
#pragma unroll
        for (int ii = 0; ii < 4; ii++)
#pragma unroll
            for (int jj = 0; jj < 4; jj++)
                g[ii][jj] += a[ii].x * q[jj].x + a[ii].y * q[jj].y;
#pragma unroll
        for (int ii = 0; ii < 8; ii++)
#pragma unroll
            for (int jj = 0; jj < 4; jj++)
                kk[ii][jj] += c[ii].x * q[jj].x + c[ii].y * q[jj].y;
    }

    __syncthreads();  // xs reads done before cbuf overwrites the union

    if (mg > 0) {
        float* p = cbuf + ((mg - 1) * 64 + lane) * 52;
#pragma unroll
        for (int ii = 0; ii < 4; ii++) *(float4*)&p[ii * 4] = *(float4*)&g[ii][0];
#pragma unroll
        for (int ii = 0; ii < 8; ii++) *(float4*)&p[16 + ii * 4] = *(float4*)&kk[ii][0];
    }
    __syncthreads();
    if (mg == 0) {
#pragma unroll
        for (int w = 0; w < 3; w++) {
            const float* p = cbuf + (w * 64 + lane) * 52;
#pragma unroll
            for (int ii = 0; ii < 4; ii++) {
                float4 v = *(const float4*)&p[ii * 4];
                g[ii][0] += v.x; g[ii][1] += v.y; g[ii][2] += v.z; g[ii][3] += v.w;
            }
#pragma unroll
            for (int ii = 0; ii < 8; ii++) {
                float4 v = *(const float4*)&p[16 + ii * 4];
                kk[ii][0] += v.x; kk[ii][1] += v.y; kk[ii][2] += v.z; kk[ii][3] += v.w;
            }
        }
        float* pg = Pg + (size_t)blk * 1024;
#pragma unroll
        for (int ii = 0; ii < 4; ii++)
            *(float4*)&pg[(i0 + ii) * 32 + d0] = *(float4*)&g[ii][0];
        float* pk = Pk + (size_t)blk * 2048;
#pragma unroll
        for (int ii = 0; ii < 8; ii++)
            *(float4*)&pk[(i4 + 8 * ii) * 32 + d0] = *(float4*)&kk[ii][0];
    }
}

// ---------------------------------------------------------------------------
// K1b (NEW): parallel partial reduction. Grid 256 = 16 b x 16 row-groups of
// 6 rows; 192 active threads = 6 rows x 32 cols; each sums NPART=64 partials
// (coalesced 128B/row segments; Pg/Pk branch is wave-uniform: each wave
// covers exactly 2 rows, never straddling the row-32 boundary). Replaces
// k_chain's 16-block serial 12 MB read (BW-starved at 6% of CUs) with a
// 256-block 12 MB read -> full-chip BW.
// ---------------------------------------------------------------------------
__global__ __launch_bounds__(256) void k_reduce(
    const float* __restrict__ Pg, const float* __restrict__ Pk,
    float* __restrict__ R)
{
    const int blk = blockIdx.x;
    const int b = blk >> 4;
    const int rg = blk & 15;
    const int t = threadIdx.x;
    if (t >= 192) return;
    const int row6 = t >> 5;          // 0..5
    const int col = t & 31;
    const int gr = rg * 6 + row6;     // 0..95
    const float* src;
    size_t stride;
    if (gr < 32) { src = Pg + (size_t)b * USTRIDE + gr * 32 + col;          stride = 1024; }
    else         { src = Pk + (size_t)b * NPART * 2048 + (gr - 32) * 32 + col; stride = 2048; }
    float s = 0.f;
#pragma unroll 8
    for (int p = 0; p < NPART; p++) s += src[(size_t)p * stride];
    R[(size_t)b * 3072 + gr * 32 + col] = s;
}

// ---------------------------------------------------------------------------
// K2a: one block per batch. Load reduced G (32x32), K (64x32) from R (48 KB
// per batch, L2-hot); run the tiny layer chain; write U (64x32) into the
// head of this batch's Pg region (partials already consumed by k_reduce;
// kernel boundary orders it).  PgU NOT __restrict__ (alias by design).
// ---------------------------------------------------------------------------
__global__ __launch_bounds__(256) void k_chain(
    float* PgU, const float* __restrict__ R,
    const float* __restrict__ alpha, const float* __restrict__ kp,
    const float* __restrict__ emb, const float* __restrict__ Mm)
{
    __shared__ float G_s[32][36];
    __shared__ float K_s[64][36];
    __shared__ float C_s[64][36];
    __shared__ float W_s[64][36];
    __shared__ float T_s[64][36];
    const int t = threadIdx.x;
    const int b = blockIdx.x;
    const float* Rb = R + (size_t)b * 3072;

    // ---- load reduced G,K (1 + 2 float4 per thread) ----
    {
        const int row = t >> 3, col = (t & 7) << 2;
        *(float4*)&G_s[row][col] = *(const float4*)&Rb[row * 32 + col];
        const int row0 = t >> 2, col2 = (t & 3) << 3;
        *(float4*)&K_s[row0][col2]     = *(const float4*)&Rb[1024 + row0 * 32 + col2];
        *(float4*)&K_s[row0][col2 + 4] = *(const float4*)&Rb[1024 + row0 * 32 + col2 + 4];
    }
    __syncthreads();

    // ---- tiny chain: C0 = emb.K; l: W += f*C; C += M.(f*C.G) (l<2) ----
    const int r  = t >> 2;         // 0..63
    const int dd = (t & 3) << 3;   // 0,8,16,24
    {
        const float* er = emb + r * EMBD;
        float acc[8];
#pragma unroll
        for (int j = 0; j < 8; j++) acc[j] = 0.f;
        for (int c = 0; c < 64; c++) {
            const float e = er[c];
#pragma unroll
            for (int j = 0; j < 8; j++) acc[j] += e * K_s[c][dd + j];
        }
#pragma unroll
        for (int j = 0; j < 8; j++) C_s[r][dd + j] = acc[j];
    }
    __syncthreads();

    const float scale = kp[0] * (1.f / (float)NCTX);
    for (int l = 0; l < 3; l++) {
        const float f = scale * alpha[l * EMBD + r];
#pragma unroll
        for (int j = 0; j < 8; j++) {
            const float w = f * C_s[r][dd + j];
            if (l == 0) W_s[r][dd + j] = w; else W_s[r][dd + j] += w;
        }
        if (l < 2) {
            float tacc[8];
#pragma unroll
            for (int j = 0; j < 8; j++) tacc[j] = 0.f;
            for (int d = 0; d < 32; d++) {
                const float cv = C_s[r][d];
#pragma unroll
                for (int j = 0; j < 8; j++) tacc[j] += cv * G_s[d][dd + j];
            }
#pragma unroll
            for (int j = 0; j < 8; j++) T_s[r][dd + j] = f * tacc[j];
            __syncthreads();
            const float* Mr = Mm + r * EMBD;
            float uacc[8];
#pragma unroll
            for (int j = 0; j < 8; j++) uacc[j] = 0.f;
            for (int jj = 0; jj < 64; jj++) {
                const float mv = Mr[jj];
#pragma unroll
                for (int j = 0; j < 8; j++) uacc[j] += mv * T_s[jj][dd + j];
            }
#pragma unroll
            for (int j = 0; j < 8; j++) C_s[r][dd + j] += uacc[j];
            __syncthreads();
        }
    }
    __syncthreads();

    // ---- U[c][d] = sum_e emb[e][c] * W[e][d] -> head of Pg region ----
    {
        float acc[8];
#pragma unroll
        for (int j = 0; j < 8; j++) acc[j] = 0.f;
        for (int e = 0; e < 64; e++) {
            const float ev = emb[e * EMBD + r];
#pragma unroll
            for (int j = 0; j < 8; j++) acc[j] += ev * W_s[e][dd + j];
        }
        float* ub = PgU + (size_t)b * USTRIDE + r * 32 + dd;
        float4 v0 = {acc[0], acc[1], acc[2], acc[3]};
        float4 v1 = {acc[4], acc[5], acc[6], acc[7]};
        *(float4*)&ub[0] = v0;
        *(float4*)&ub[4] = v1;
    }
}

// ---------------------------------------------------------------------------
// K2b: epilogue. Grid 1024 = 16 b x 64 tiles of 32 cols.  [UNCHANGED r9]
// ---------------------------------------------------------------------------
__global__ __launch_bounds__(256, 4) void k_out(
    const float* __restrict__ x, const float* __restrict__ Ug,
    const float* __restrict__ emb, float* __restrict__ out)
{
    __shared__ float U_s[64][32];
    __shared__ float xt_s[96 * SS2];
    __shared__ float lg_s[32 * 65];
    const int t = threadIdx.x;
    const int blk = blockIdx.x;
    const int b = blk >> 6;
    const int tile = blk & 63;
    const int n0 = tile << 5;
    const float* xb = x + (size_t)b * DIN * NN;

    {
        const float* ub = Ug + (size_t)b * USTRIDE + t * 8;
        float4 v0 = *(const float4*)&ub[0];
        float4 v1 = *(const float4*)&ub[4];
        float* d = &U_s[0][0] + t * 8;
        *(float4*)&d[0] = v0;
        *(float4*)&d[4] = v1;
    }
    for (int idx = t; idx < 96 * 16; idx += 256) {
        const int r = idx >> 4;
        const int mc = (idx & 15) << 1;
        const int gr = (r < IS) ? r : (r + NCAT);
        float2 v = *(const float2*)&xb[gr * NN + n0 + mc];
        *(float2*)&xt_s[r * SS2 + mc] = v;
    }
    __syncthreads();

    const int nl = t & 31;
    const int h = t >> 5;
    const int c0 = h << 3;
    const int n = n0 + nl;

    float xq[IS];
#pragma unroll
    for (int d = 0; d < IS; d++) xq[d] = xt_s[d * SS2 + nl];

    float lg[8];
#pragma unroll
    for (int cl = 0; cl < 8; cl++) {
        const float* Ur = &U_s[c0 + cl][0];
        float s = 0.f;
#pragma unroll
        for (int k = 0; k < 8; k++) {
            float4 u = *(const float4*)&Ur[4 * k];
            s += u.x * xq[4*k] + u.y * xq[4*k+1] + u.z * xq[4*k+2] + u.w * xq[4*k+3];
        }
        lg[cl] = s;
    }
#pragma unroll 8
    for (int e = 0; e < 64; e++) {
        const float tv = xt_s[(IS + e) * SS2 + nl];
        const float* er = emb + e * EMBD + c0;
        float4 e0 = *(const float4*)&er[0];
        float4 e1 = *(const float4*)&er[4];
        lg[0] += e0.x * tv; lg[1] += e0.y * tv; lg[2] += e0.z * tv; lg[3] += e0.w * tv;
        lg[4] += e1.x * tv; lg[5] += e1.y * tv; lg[6] += e1.z * tv; lg[7] += e1.w * tv;
    }

    const size_t base = ((size_t)b * NN + n) * (size_t)NCAT;
    float* lo = out + base + c0;
    {
        float4 v0 = {lg[0], lg[1], lg[2], lg[3]};
        float4 v1 = {lg[4], lg[5], lg[6], lg[7]};
        *(float4*)&lo[0] = v0;
        *(float4*)&lo[4] = v1;
    }
    float* ls = &lg_s[nl * 65 + c0];
#pragma unroll
    for (int cl = 0; cl < 8; cl++) ls[cl] = lg[cl];
    __syncthreads();

    const float* row = &lg_s[nl * 65];
    float mx = row[0];
#pragma unroll
    for (int c = 1; c < 64; c++) mx = fmaxf(mx, row[c]);

    float p[8];
    float sum = 0.f;
#pragma unroll
    for (int c = 0; c < 64; c++) {
        const float e = __expf(row[c] - mx);
        sum += e;
        if ((c >> 3) == h) p[c & 7] = e;
    }

    const float inv = 1.f / sum;
    float* po = out + (size_t)BB * NN * NCAT + base + c0;
    {
        float4 v0 = {p[0]*inv, p[1]*inv, p[2]*inv, p[3]*inv};
        float4 v1 = {p[4]*inv, p[5]*inv, p[6]*inv, p[7]*inv};
        *(float4*)&po[0] = v0;
        *(float4*)&po[4] = v1;
    }
}

extern "C" void kernel_launch(void* const* d_in, const int* in_sizes, int n_in,
                              void* d_out, int out_size, void* d_ws, size_t ws_size,
                              hipStream_t stream) {
    const float* x     = (const float*)d_in[0];
    const float* alpha = (const float*)d_in[1];
    const float* kp    = (const float*)d_in[2];
    const float* emb   = (const float*)d_in[3];
    const float* Mmat  = (const float*)d_in[4];
    float* out = (float*)d_out;

    float* Pg = (float*)d_ws;                 // 1024*1024 fl (U reuses head/batch)
    float* Pk = Pg + (size_t)GRID1 * 1024;    // 1024*2048 fl
    float* R  = (float*)d_ws + ROFF;          // 16*3072 fl reduced G|K

    k_gram  <<<GRID1, 256, 0, stream>>>(x, Pg, Pk);
    k_reduce<<<256,   256, 0, stream>>>(Pg, Pk, R);
    k_chain <<<BB,    256, 0, stream>>>(Pg, R, alpha, kp, emb, Mmat);
    k_out   <<<BB*64, 256, 0, stream>>>(x, Pg, emb, out);
}

// Round 11
// 123.705 us; speedup vs baseline: 1.0349x; 1.0041x over previous
//
#include <hip/hip_runtime.h>

#define BB 16
#define NN 2048
#define DIN 160
#define IS 32
#define NCAT 64
#define EMBD 64
#define NCTX 2047
#define NT1 32               // 64-col tiles per batch (K1)
#define GRID1 (BB * NT1)     // 512
#define SS1 66               // LDS row stride (floats) for xs[96][SS1]
#define NPART NT1            // partials per batch (32)
#define USTRIDE (NPART * 1024)  // per-batch float stride in Pg region; U reuses head
#define SS2 34               // k_out staging stride
// R (reduced G|K, [b][96][32]) lives after Pg and Pk in ws
#define ROFF ((size_t)GRID1 * 1024 + (size_t)GRID1 * 2048)

// ---------------------------------------------------------------------------
// K1: per-tile partial G = xq.xq^T (32x32), K = xcat.xq^T (64x32), 64-col
// tiles. Block 256 = 4 waves; wave mg covers 16 m's. LDS: staging xs[96][66]
// (25.3 KB) UNIONED with cbuf (39.9 KB), temporally disjoint and barrier-
// separated -> 39.9 KB total -> 4 blocks/CU (vs round-8's 65 KB / 2 blocks).
// vs round-9: same occupancy, HALF the partial traffic (6 MB not 12) and
// half the per-tile staging overhead.
// ---------------------------------------------------------------------------
__global__ __launch_bounds__(256, 4) void k_gram(
    const float* __restrict__ x,
    float* __restrict__ Pg, float* __restrict__ Pk)
{
    __shared__ float smem[3 * 64 * 52];  // 39,936 B; xs (6336 fl) ∪ cbuf (9984 fl)
    float* xs = smem;
    float* cbuf = smem;
    const int t = threadIdx.x;
    const int blk = blockIdx.x;
    const int b = blk >> 5;
    const int tile = blk & 31;
    const int n0 = tile << 6;
    const float* xb = x + (size_t)b * DIN * NN;

    // stage rows 0..95 x 64 cols (coalesced float2; mask out global col 2047)
    for (int idx = t; idx < 96 * 32; idx += 256) {
        const int r = idx >> 5;
        const int mc = (idx & 31) << 1;
        float2 v = *(const float2*)&xb[r * NN + n0 + mc];
        if (n0 + mc + 1 == NCTX) v.y = 0.f;
        *(float2*)&xs[r * SS1 + mc] = v;
    }
    __syncthreads();

    const int mg = t >> 6;      // wave id -> m range (16 cols each)
    const int lane = t & 63;
    const int i4 = lane >> 3;   // 0..7
    const int d4 = lane & 7;    // 0..7
    const int i0 = i4 << 2;
    const int d0 = d4 << 2;
    const int m0 = mg << 4;

    float g[4][4], kk[8][4];
#pragma unroll
    for (int ii = 0; ii < 4; ii++)
#pragma unroll
        for (int jj = 0; jj < 4; jj++) g[ii][jj] = 0.f;
#pragma unroll
    for (int ii = 0; ii < 8; ii++)
#pragma unroll
        for (int jj = 0; jj < 4; jj++) kk[ii][jj] = 0.f;

    for (int m = m0; m < m0 + 16; m += 2) {
        float2 q[4], a[4], c[8];
#pragma unroll
        for (int j = 0; j < 4; j++) q[j] = *(const float2*)&xs[(d0 + j) * SS1 + m];
#pragma unroll
        for (int j = 0; j < 4; j++) a[j] = *(const float2*)&xs[(i0 + j) * SS1 + m];
#pragma unroll
        for (int j = 0; j < 8; j++) c[j] = *(const float2*)&xs[(32 + i4 + 8 * j) * SS1 + m];
#pragma unroll
        for (int ii = 0; ii < 4; ii++)
#pragma unroll
            for (int jj = 0; jj < 4; jj++)
                g[ii][jj] += a[ii].x * q[jj].x + a[ii].y * q[jj].y;
#pragma unroll
        for (int ii = 0; ii < 8; ii++)
#pragma unroll
            for (int jj = 0; jj < 4; jj++)
                kk[ii][jj] += c[ii].x * q[jj].x + c[ii].y * q[jj].y;
    }

    __syncthreads();  // all xs reads complete before cbuf overwrites the union

    // cross-wave reduce via cbuf (stride 52 spreads banks)
    if (mg > 0) {
        float* p = cbuf + ((mg - 1) * 64 + lane) * 52;
#pragma unroll
        for (int ii = 0; ii < 4; ii++) *(float4*)&p[ii * 4] = *(float4*)&g[ii][0];
#pragma unroll
        for (int ii = 0; ii < 8; ii++) *(float4*)&p[16 + ii * 4] = *(float4*)&kk[ii][0];
    }
    __syncthreads();
    if (mg == 0) {
#pragma unroll
        for (int w = 0; w < 3; w++) {
            const float* p = cbuf + (w * 64 + lane) * 52;
#pragma unroll
            for (int ii = 0; ii < 4; ii++) {
                float4 v = *(const float4*)&p[ii * 4];
                g[ii][0] += v.x; g[ii][1] += v.y; g[ii][2] += v.z; g[ii][3] += v.w;
            }
#pragma unroll
            for (int ii = 0; ii < 8; ii++) {
                float4 v = *(const float4*)&p[16 + ii * 4];
                kk[ii][0] += v.x; kk[ii][1] += v.y; kk[ii][2] += v.z; kk[ii][3] += v.w;
            }
        }
        float* pg = Pg + (size_t)blk * 1024;
#pragma unroll
        for (int ii = 0; ii < 4; ii++)
            *(float4*)&pg[(i0 + ii) * 32 + d0] = *(float4*)&g[ii][0];
        float* pk = Pk + (size_t)blk * 2048;
#pragma unroll
        for (int ii = 0; ii < 8; ii++)
            *(float4*)&pk[(i4 + 8 * ii) * 32 + d0] = *(float4*)&kk[ii][0];
    }
}

// ---------------------------------------------------------------------------
// K1b: parallel partial reduction. Grid 256 = 16 b x 16 row-groups of 6 rows;
// 192 active threads = 6 rows x 32 cols; each sums NPART=32 partials
// (coalesced 128B/row segments; Pg/Pk branch wave-uniform). Full-chip BW.
// ---------------------------------------------------------------------------
__global__ __launch_bounds__(256) void k_reduce(
    const float* __restrict__ Pg, const float* __restrict__ Pk,
    float* __restrict__ R)
{
    const int blk = blockIdx.x;
    const int b = blk >> 4;
    const int rg = blk & 15;
    const int t = threadIdx.x;
    if (t >= 192) return;
    const int row6 = t >> 5;          // 0..5
    const int col = t & 31;
    const int gr = rg * 6 + row6;     // 0..95
    const float* src;
    size_t stride;
    if (gr < 32) { src = Pg + (size_t)b * USTRIDE + gr * 32 + col;             stride = 1024; }
    else         { src = Pk + (size_t)b * NPART * 2048 + (gr - 32) * 32 + col; stride = 2048; }
    float s = 0.f;
#pragma unroll 8
    for (int p = 0; p < NPART; p++) s += src[(size_t)p * stride];
    R[(size_t)b * 3072 + gr * 32 + col] = s;
}

// ---------------------------------------------------------------------------
// K2a: one block per batch. Load reduced G (32x32), K (64x32) from R (192 KB
// total, L2-hot); run the tiny layer chain; write U (64x32) into the head of
// this batch's Pg region.  PgU NOT __restrict__ (alias by design).
// ---------------------------------------------------------------------------
__global__ __launch_bounds__(256) void k_chain(
    float* PgU, const float* __restrict__ R,
    const float* __restrict__ alpha, const float* __restrict__ kp,
    const float* __restrict__ emb, const float* __restrict__ Mm)
{
    __shared__ float G_s[32][36];
    __shared__ float K_s[64][36];
    __shared__ float C_s[64][36];
    __shared__ float W_s[64][36];
    __shared__ float T_s[64][36];
    const int t = threadIdx.x;
    const int b = blockIdx.x;
    const float* Rb = R + (size_t)b * 3072;

    {
        const int row = t >> 3, col = (t & 7) << 2;
        *(float4*)&G_s[row][col] = *(const float4*)&Rb[row * 32 + col];
        const int row0 = t >> 2, col2 = (t & 3) << 3;
        *(float4*)&K_s[row0][col2]     = *(const float4*)&Rb[1024 + row0 * 32 + col2];
        *(float4*)&K_s[row0][col2 + 4] = *(const float4*)&Rb[1024 + row0 * 32 + col2 + 4];
    }
    __syncthreads();

    const int r  = t >> 2;         // 0..63
    const int dd = (t & 3) << 3;   // 0,8,16,24
    {
        const float* er = emb + r * EMBD;
        float acc[8];
#pragma unroll
        for (int j = 0; j < 8; j++) acc[j] = 0.f;
        for (int c = 0; c < 64; c++) {
            const float e = er[c];
#pragma unroll
            for (int j = 0; j < 8; j++) acc[j] += e * K_s[c][dd + j];
        }
#pragma unroll
        for (int j = 0; j < 8; j++) C_s[r][dd + j] = acc[j];
    }
    __syncthreads();

    const float scale = kp[0] * (1.f / (float)NCTX);
    for (int l = 0; l < 3; l++) {
        const float f = scale * alpha[l * EMBD + r];
#pragma unroll
        for (int j = 0; j < 8; j++) {
            const float w = f * C_s[r][dd + j];
            if (l == 0) W_s[r][dd + j] = w; else W_s[r][dd + j] += w;
        }
        if (l < 2) {
            float tacc[8];
#pragma unroll
            for (int j = 0; j < 8; j++) tacc[j] = 0.f;
            for (int d = 0; d < 32; d++) {
                const float cv = C_s[r][d];
#pragma unroll
                for (int j = 0; j < 8; j++) tacc[j] += cv * G_s[d][dd + j];
            }
#pragma unroll
            for (int j = 0; j < 8; j++) T_s[r][dd + j] = f * tacc[j];
            __syncthreads();
            const float* Mr = Mm + r * EMBD;
            float uacc[8];
#pragma unroll
            for (int j = 0; j < 8; j++) uacc[j] = 0.f;
            for (int jj = 0; jj < 64; jj++) {
                const float mv = Mr[jj];
#pragma unroll
                for (int j = 0; j < 8; j++) uacc[j] += mv * T_s[jj][dd + j];
            }
#pragma unroll
            for (int j = 0; j < 8; j++) C_s[r][dd + j] += uacc[j];
            __syncthreads();
        }
    }
    __syncthreads();

    {
        float acc[8];
#pragma unroll
        for (int j = 0; j < 8; j++) acc[j] = 0.f;
        for (int e = 0; e < 64; e++) {
            const float ev = emb[e * EMBD + r];
#pragma unroll
            for (int j = 0; j < 8; j++) acc[j] += ev * W_s[e][dd + j];
        }
        float* ub = PgU + (size_t)b * USTRIDE + r * 32 + dd;
        float4 v0 = {acc[0], acc[1], acc[2], acc[3]};
        float4 v1 = {acc[4], acc[5], acc[6], acc[7]};
        *(float4*)&ub[0] = v0;
        *(float4*)&ub[4] = v1;
    }
}

// ---------------------------------------------------------------------------
// K2b: epilogue. Grid 1024 = 16 b x 64 tiles of 32 cols; 4 blocks/CU.
// [UNCHANGED r9/r10]
// ---------------------------------------------------------------------------
__global__ __launch_bounds__(256, 4) void k_out(
    const float* __restrict__ x, const float* __restrict__ Ug,
    const float* __restrict__ emb, float* __restrict__ out)
{
    __shared__ float U_s[64][32];
    __shared__ float xt_s[96 * SS2];
    __shared__ float lg_s[32 * 65];
    const int t = threadIdx.x;
    const int blk = blockIdx.x;
    const int b = blk >> 6;
    const int tile = blk & 63;
    const int n0 = tile << 5;
    const float* xb = x + (size_t)b * DIN * NN;

    {
        const float* ub = Ug + (size_t)b * USTRIDE + t * 8;
        float4 v0 = *(const float4*)&ub[0];
        float4 v1 = *(const float4*)&ub[4];
        float* d = &U_s[0][0] + t * 8;
        *(float4*)&d[0] = v0;
        *(float4*)&d[4] = v1;
    }
    for (int idx = t; idx < 96 * 16; idx += 256) {
        const int r = idx >> 4;
        const int mc = (idx & 15) << 1;
        const int gr = (r < IS) ? r : (r + NCAT);
        float2 v = *(const float2*)&xb[gr * NN + n0 + mc];
        *(float2*)&xt_s[r * SS2 + mc] = v;
    }
    __syncthreads();

    const int nl = t & 31;
    const int h = t >> 5;
    const int c0 = h << 3;
    const int n = n0 + nl;

    float xq[IS];
#pragma unroll
    for (int d = 0; d < IS; d++) xq[d] = xt_s[d * SS2 + nl];

    float lg[8];
#pragma unroll
    for (int cl = 0; cl < 8; cl++) {
        const float* Ur = &U_s[c0 + cl][0];
        float s = 0.f;
#pragma unroll
        for (int k = 0; k < 8; k++) {
            float4 u = *(const float4*)&Ur[4 * k];
            s += u.x * xq[4*k] + u.y * xq[4*k+1] + u.z * xq[4*k+2] + u.w * xq[4*k+3];
        }
        lg[cl] = s;
    }
#pragma unroll 8
    for (int e = 0; e < 64; e++) {
        const float tv = xt_s[(IS + e) * SS2 + nl];
        const float* er = emb + e * EMBD + c0;
        float4 e0 = *(const float4*)&er[0];
        float4 e1 = *(const float4*)&er[4];
        lg[0] += e0.x * tv; lg[1] += e0.y * tv; lg[2] += e0.z * tv; lg[3] += e0.w * tv;
        lg[4] += e1.x * tv; lg[5] += e1.y * tv; lg[6] += e1.z * tv; lg[7] += e1.w * tv;
    }

    const size_t base = ((size_t)b * NN + n) * (size_t)NCAT;
    float* lo = out + base + c0;
    {
        float4 v0 = {lg[0], lg[1], lg[2], lg[3]};
        float4 v1 = {lg[4], lg[5], lg[6], lg[7]};
        *(float4*)&lo[0] = v0;
        *(float4*)&lo[4] = v1;
    }
    float* ls = &lg_s[nl * 65 + c0];
#pragma unroll
    for (int cl = 0; cl < 8; cl++) ls[cl] = lg[cl];
    __syncthreads();

    const float* row = &lg_s[nl * 65];
    float mx = row[0];
#pragma unroll
    for (int c = 1; c < 64; c++) mx = fmaxf(mx, row[c]);

    float p[8];
    float sum = 0.f;
#pragma unroll
    for (int c = 0; c < 64; c++) {
        const float e = __expf(row[c] - mx);
        sum += e;
        if ((c >> 3) == h) p[c & 7] = e;
    }

    const float inv = 1.f / sum;
    float* po = out + (size_t)BB * NN * NCAT + base + c0;
    {
        float4 v0 = {p[0]*inv, p[1]*inv, p[2]*inv, p[3]*inv};
        float4 v1 = {p[4]*inv, p[5]*inv, p[6]*inv, p[7]*inv};
        *(float4*)&po[0] = v0;
        *(float4*)&po[4] = v1;
    }
}

extern "C" void kernel_launch(void* const* d_in, const int* in_sizes, int n_in,
                              void* d_out, int out_size, void* d_ws, size_t ws_size,
                              hipStream_t stream) {
    const float* x     = (const float*)d_in[0];
    const float* alpha = (const float*)d_in[1];
    const float* kp    = (const float*)d_in[2];
    const float* emb   = (const float*)d_in[3];
    const float* Mmat  = (const float*)d_in[4];
    float* out = (float*)d_out;

    float* Pg = (float*)d_ws;                 // 512*1024 fl (U reuses head/batch)
    float* Pk = Pg + (size_t)GRID1 * 1024;    // 512*2048 fl
    float* R  = (float*)d_ws + ROFF;          // 16*3072 fl reduced G|K

    k_gram  <<<GRID1, 256, 0, stream>>>(x, Pg, Pk);
    k_reduce<<<256,   256, 0, stream>>>(Pg, Pk, R);
    k_chain <<<BB,    256, 0, stream>>>(Pg, R, alpha, kp, emb, Mmat);
    k_out   <<<BB*64, 256, 0, stream>>>(x, Pg, emb, out);
}